// Round 3
// baseline (695.015 us; speedup 1.0000x reference)
//
#include <hip/hip_runtime.h>
#include <cmath>

// Problem constants (from reference setup_inputs)
constexpr int Bdim = 64;
constexpr int Fdim = 4096;
constexpr int Edim = 256;
constexpr int Hdim = 512;
constexpr int Udim = 512;

typedef __attribute__((ext_vector_type(8))) short short8;   // 8 bf16 (16B)
typedef __attribute__((ext_vector_type(4))) float f32x4;

// ---------------------------------------------------------------------------
// Helpers: fp32 -> bf16 (RNE), fast tanh
// ---------------------------------------------------------------------------
__device__ __forceinline__ unsigned short f2bf(float f) {
    unsigned int u = __float_as_uint(f);
    u += 0x7FFFu + ((u >> 16) & 1u);   // RNE; inputs finite
    return (unsigned short)(u >> 16);
}
__device__ __forceinline__ unsigned int pack2(float lo, float hi) {
    return (unsigned int)f2bf(lo) | ((unsigned int)f2bf(hi) << 16);
}
__device__ __forceinline__ float tanh_fast(float x) {
    float e = __expf(2.0f * x);
    return 1.0f - 2.0f * __builtin_amdgcn_rcpf(e + 1.0f);
}

// ---------------------------------------------------------------------------
// Kernel 1: c[b][u] = W1_b[u] + W2_b[u] + sum_h hidden[b,h] * W2_w[h,u]
// ---------------------------------------------------------------------------
__global__ __launch_bounds__(256) void proj_h_kernel(
    const float* __restrict__ hidden, const float* __restrict__ W2,
    const float* __restrict__ W1b, const float* __restrict__ W2b,
    float* __restrict__ cb)
{
    const int b = blockIdx.x;
    const int tid = threadIdx.x;
    const float* hb = hidden + (size_t)b * Hdim;
    for (int u = tid; u < Udim; u += 256) {
        float acc = 0.f;
        #pragma unroll 8
        for (int h = 0; h < Hdim; ++h)
            acc = fmaf(hb[h], W2[(size_t)h * Udim + u], acc);
        cb[(size_t)b * Udim + u] = acc + W1b[u] + W2b[u];
    }
}

// ---------------------------------------------------------------------------
// Prep: W1 (E,U) fp32 -> transposed bf16 [U][E], LDS-tiled, coalesced writes
// ---------------------------------------------------------------------------
__global__ __launch_bounds__(256) void w1t_kernel(
    const float* __restrict__ W1, unsigned short* __restrict__ Th)
{
    __shared__ unsigned short sT[64][72];          // 144B row stride (16B mult)
    const int e0 = blockIdx.x * 64, u0 = blockIdx.y * 64;
    const int tid = threadIdx.x;
    const int ue = tid & 63, er = tid >> 6;
    #pragma unroll
    for (int it = 0; it < 16; ++it) {
        const int e = er + it * 4;                 // 0..63
        sT[ue][e] = f2bf(W1[(size_t)(e0 + e) * Udim + u0 + ue]);
    }
    __syncthreads();
    const int ur = tid >> 2, c0 = (tid & 3) * 16;
    uint4 a  = *(const uint4*)&sT[ur][c0];
    uint4 b2 = *(const uint4*)&sT[ur][c0 + 8];
    unsigned short* dst = Th + (size_t)(u0 + ur) * Edim + e0 + c0;
    *(uint4*)dst = a;
    *(uint4*)(dst + 8) = b2;
}

// ---------------------------------------------------------------------------
// Kernel 2 (dominant): scores via bf16 MFMA, zero LDS / zero barriers.
// Wave tile = 32f x 32u (mi=2, nj=2), u-loop over 16 tiles covers U=512.
// A (features) read once from HBM fp32, converted to bf16 frags in regs
// (full E per wave). B frags streamed from L2 with a depth-3 pipeline.
// Epilogue per u-tile fuses tanh + V-dot into running per-f partials.
// ---------------------------------------------------------------------------
__global__ __launch_bounds__(256, 3) void score_mfma2_kernel(
    const float* __restrict__ feat,            // [B][F][E] fp32
    const unsigned short* __restrict__ W1Th,   // [U][E] bf16 hi
    const float* __restrict__ Vw, const float* __restrict__ Vb,
    const float* __restrict__ cb, float* __restrict__ scores)
{
    const int b    = blockIdx.y;
    const int f0   = blockIdx.x * 128;
    const int tid  = threadIdx.x;
    const int lane = tid & 63;
    const int w    = tid >> 6;        // 4 waves, each 32 f-rows
    const int ln15 = lane & 15;
    const int kq   = lane >> 4;       // 0..3, k-quad

    // ---- Load + convert A fragments: 2 mi x 8 k-chunks, full E ----
    short8 af[2][8];
    {
        const float* abase =
            feat + ((size_t)b * Fdim + f0 + w * 32 + ln15) * Edim + kq * 8;
        #pragma unroll
        for (int mi = 0; mi < 2; ++mi) {
            const float* ap = abase + (size_t)mi * 16 * Edim;
            #pragma unroll
            for (int kc = 0; kc < 8; ++kc) {
                float4 x = *(const float4*)(ap + kc * 32);
                float4 y = *(const float4*)(ap + kc * 32 + 4);
                uint4 u;
                u.x = pack2(x.x, x.y); u.y = pack2(x.z, x.w);
                u.z = pack2(y.x, y.y); u.w = pack2(y.z, y.w);
                af[mi][kc] = *(short8*)&u;
            }
        }
    }

    // ---- B fragment pipeline: 4 rotating buffers, depth-3 prefetch ----
    // frag(t = ut*8+k8, nj): W1Th[(ut*32 + nj*16 + ln15)*256 + k8*32 + kq*8]
    const unsigned short* bB = W1Th + ((size_t)ln15 << 8) + kq * 8;
    short8 bf[4][2];
    #pragma unroll
    for (int t = 0; t < 3; ++t) {
        const unsigned short* lp = bB + t * 32;
        bf[t][0] = *(const short8*)lp;
        bf[t][1] = *(const short8*)(lp + 4096);
    }

    float sacc[2][4] = {};

    for (int ut = 0; ut < 16; ++ut) {
        const unsigned short* pu = bB + (size_t)ut * 8192;
        float cu[2], vv[2];
        f32x4 acc[2][2] = {};
        #pragma unroll
        for (int i = 0; i < 8; ++i) {
            if (i == 0) {      // prefetch bias/V for this u-tile (used at i==7)
                #pragma unroll
                for (int nj = 0; nj < 2; ++nj) {
                    const int u = ut * 32 + nj * 16 + ln15;
                    cu[nj] = cb[(size_t)b * Udim + u];
                    vv[nj] = Vw[u];
                }
            }
            {   // prefetch B frags for t+3 (tail over-read lands in ws slack)
                const unsigned short* lp =
                    pu + ((i + 3 >= 8) ? (8192 + (i - 5) * 32) : ((i + 3) * 32));
                const int s = (i + 3) & 3;
                bf[s][0] = *(const short8*)lp;
                bf[s][1] = *(const short8*)(lp + 4096);
            }
            #pragma unroll
            for (int mi = 0; mi < 2; ++mi)
                #pragma unroll
                for (int nj = 0; nj < 2; ++nj)
                    acc[mi][nj] = __builtin_amdgcn_mfma_f32_16x16x32_bf16(
                        af[mi][i], bf[i & 3][nj], acc[mi][nj], 0, 0, 0);
            if (i == 7) {      // fused epilogue: tanh + V-dot
                #pragma unroll
                for (int mi = 0; mi < 2; ++mi)
                    #pragma unroll
                    for (int r = 0; r < 4; ++r)
                        sacc[mi][r] += tanh_fast(acc[mi][0][r] + cu[0]) * vv[0]
                                     + tanh_fast(acc[mi][1][r] + cu[1]) * vv[1];
            }
        }
    }

    // ---- Reduce over u-lanes (ln15) and store final scores (+Vb) ----
    const float vb = Vb[0];
    #pragma unroll
    for (int mi = 0; mi < 2; ++mi)
        #pragma unroll
        for (int r = 0; r < 4; ++r) {
            float s = sacc[mi][r];
            s += __shfl_xor(s, 1);
            s += __shfl_xor(s, 2);
            s += __shfl_xor(s, 4);
            s += __shfl_xor(s, 8);
            if (ln15 == 0) {
                const int f = f0 + w * 32 + mi * 16 + kq * 4 + r;
                scores[(size_t)b * Fdim + f] = s + vb;
            }
        }
}

// ---------------------------------------------------------------------------
// Fallback fp32 score kernel (round-1) — used only if ws too small
// ---------------------------------------------------------------------------
constexpr int TFt = 64;
constexpr int TUt = 64;
constexpr int LDR = Edim + 4;

__global__ __launch_bounds__(256) void score_kernel(
    const float* __restrict__ feat, const float* __restrict__ W1,
    const float* __restrict__ Vw, const float* __restrict__ Vb,
    const float* __restrict__ cb, float* __restrict__ scores)
{
    __shared__ float sA[TFt * LDR];
    __shared__ float sW[TUt * LDR];

    const int b   = blockIdx.y;
    const int f0  = blockIdx.x * TFt;
    const int tid = threadIdx.x;
    const int tf  = tid >> 4;
    const int tu  = tid & 15;

    {
        const float4* gA = (const float4*)(feat + ((size_t)b * Fdim + f0) * Edim);
        #pragma unroll
        for (int it = 0; it < 16; ++it) {
            const int i = tid + it * 256;
            const int f = i >> 6;
            const int qq = i & 63;
            const float4 v = gA[i];
            *(float4*)&sA[f * LDR + 4 * qq] = v;
        }
    }

    float sacc[4] = {0.f, 0.f, 0.f, 0.f};
    const float* cbb = cb + (size_t)b * Udim;

    for (int uc = 0; uc < Udim; uc += TUt) {
        __syncthreads();
        #pragma unroll
        for (int it = 0; it < 16; ++it) {
            const int i = tid + it * 256;
            const int e = i >> 4;
            const int qq = i & 15;
            const float4 v = *(const float4*)(W1 + (size_t)e * Udim + uc + 4 * qq);
            sW[(4 * qq + 0) * LDR + e] = v.x;
            sW[(4 * qq + 1) * LDR + e] = v.y;
            sW[(4 * qq + 2) * LDR + e] = v.z;
            sW[(4 * qq + 3) * LDR + e] = v.w;
        }
        __syncthreads();

        float acc[4][4] = {};
        #pragma unroll 4
        for (int e = 0; e < Edim; e += 4) {
            float4 a0 = *(const float4*)&sA[(tf +  0) * LDR + e];
            float4 a1 = *(const float4*)&sA[(tf + 16) * LDR + e];
            float4 a2 = *(const float4*)&sA[(tf + 32) * LDR + e];
            float4 a3 = *(const float4*)&sA[(tf + 48) * LDR + e];
            float4 w0 = *(const float4*)&sW[(tu +  0) * LDR + e];
            float4 w1 = *(const float4*)&sW[(tu + 16) * LDR + e];
            float4 w2 = *(const float4*)&sW[(tu + 32) * LDR + e];
            float4 w3 = *(const float4*)&sW[(tu + 48) * LDR + e];
            #define FMA4(i, j, A, W)                         \
                acc[i][j] = fmaf(A.x, W.x, acc[i][j]);       \
                acc[i][j] = fmaf(A.y, W.y, acc[i][j]);       \
                acc[i][j] = fmaf(A.z, W.z, acc[i][j]);       \
                acc[i][j] = fmaf(A.w, W.w, acc[i][j]);
            FMA4(0,0,a0,w0) FMA4(0,1,a0,w1) FMA4(0,2,a0,w2) FMA4(0,3,a0,w3)
            FMA4(1,0,a1,w0) FMA4(1,1,a1,w1) FMA4(1,2,a1,w2) FMA4(1,3,a1,w3)
            FMA4(2,0,a2,w0) FMA4(2,1,a2,w1) FMA4(2,2,a2,w2) FMA4(2,3,a2,w3)
            FMA4(3,0,a3,w0) FMA4(3,1,a3,w1) FMA4(3,2,a3,w2) FMA4(3,3,a3,w3)
            #undef FMA4
        }

        #pragma unroll
        for (int j = 0; j < 4; ++j) {
            const int u = uc + tu + 16 * j;
            const float vw = Vw[u];
            const float cuv = cbb[u];
            #pragma unroll
            for (int i = 0; i < 4; ++i)
                sacc[i] = fmaf(tanhf(acc[i][j] + cuv), vw, sacc[i]);
        }
    }

    const float vb = Vb[0];
    #pragma unroll
    for (int i = 0; i < 4; ++i) {
        float s = sacc[i];
        s += __shfl_xor(s, 1);
        s += __shfl_xor(s, 2);
        s += __shfl_xor(s, 4);
        s += __shfl_xor(s, 8);
        if (tu == 0)
            scores[(size_t)b * Fdim + f0 + tf + 16 * i] = s + vb;
    }
}

// ---------------------------------------------------------------------------
// Kernel 3: in-place softmax over F for each b
// ---------------------------------------------------------------------------
__global__ __launch_bounds__(256) void softmax_kernel(float* __restrict__ sc)
{
    __shared__ float red[256];
    const int b = blockIdx.x;
    const int tid = threadIdx.x;
    float* row = sc + (size_t)b * Fdim;

    float v[16];
    float m = -INFINITY;
    #pragma unroll
    for (int i = 0; i < 16; ++i) {
        v[i] = row[tid + 256 * i];
        m = fmaxf(m, v[i]);
    }
    red[tid] = m;
    __syncthreads();
    for (int s = 128; s > 0; s >>= 1) {
        if (tid < s) red[tid] = fmaxf(red[tid], red[tid + s]);
        __syncthreads();
    }
    m = red[0];
    __syncthreads();

    float sum = 0.f;
    #pragma unroll
    for (int i = 0; i < 16; ++i) {
        v[i] = expf(v[i] - m);
        sum += v[i];
    }
    red[tid] = sum;
    __syncthreads();
    for (int s = 128; s > 0; s >>= 1) {
        if (tid < s) red[tid] += red[tid + s];
        __syncthreads();
    }
    const float inv = 1.f / red[0];
    #pragma unroll
    for (int i = 0; i < 16; ++i)
        row[tid + 256 * i] = v[i] * inv;
}

// ---------------------------------------------------------------------------
// Kernel 4: context[b][e] = sum_f weights[b][f] * feat[b][f][e]
// ---------------------------------------------------------------------------
__global__ __launch_bounds__(256) void context_kernel(
    const float* __restrict__ feat, const float* __restrict__ wts,
    float* __restrict__ ctx)
{
    const int b  = blockIdx.y;
    const int fc = blockIdx.x;
    const int e  = threadIdx.x;

    const float* fp = feat + ((size_t)b * Fdim + (size_t)fc * 256) * Edim + e;
    const float* wp = wts + (size_t)b * Fdim + (size_t)fc * 256;

    float acc = 0.f;
    #pragma unroll 8
    for (int f = 0; f < 256; ++f)
        acc = fmaf(wp[f], fp[(size_t)f * Edim], acc);

    atomicAdd(&ctx[(size_t)b * Edim + e], acc);
}

// ---------------------------------------------------------------------------
extern "C" void kernel_launch(void* const* d_in, const int* in_sizes, int n_in,
                              void* d_out, int out_size, void* d_ws, size_t ws_size,
                              hipStream_t stream)
{
    const float* features = (const float*)d_in[0];
    const float* hidden   = (const float*)d_in[1];
    const float* W1w      = (const float*)d_in[2];
    const float* W1b      = (const float*)d_in[3];
    const float* W2w      = (const float*)d_in[4];
    const float* W2b      = (const float*)d_in[5];
    const float* Vw       = (const float*)d_in[6];
    const float* Vb       = (const float*)d_in[7];

    float* ctx = (float*)d_out;                       // (B,E)
    float* wts = (float*)d_out + (size_t)Bdim * Edim; // (B,F)

    // Workspace: cb (128 KiB) | W1Th (512 KiB bf16 [U][E]) | >=64 KiB slack
    // (slack absorbs the depth-3 B-prefetch tail over-read)
    float* cb = (float*)d_ws;
    unsigned short* W1Th = (unsigned short*)((char*)d_ws + 131072);
    const size_t NEED = 131072 + (size_t)Udim * Edim * 2 + 65536;   // < 1 MB

    hipMemsetAsync(ctx, 0, (size_t)Bdim * Edim * sizeof(float), stream);
    proj_h_kernel<<<Bdim, 256, 0, stream>>>(hidden, W2w, W1b, W2b, cb);

    if (ws_size >= NEED) {
        dim3 tgrid(Edim / 64, Udim / 64);   // (4, 8)
        w1t_kernel<<<tgrid, 256, 0, stream>>>(W1w, W1Th);
        dim3 sgrid(Fdim / 128, Bdim);       // (32, 64)
        score_mfma2_kernel<<<sgrid, 256, 0, stream>>>(features, W1Th, Vw, Vb, cb, wts);
    } else {
        dim3 sgrid(Fdim / TFt, Bdim);
        score_kernel<<<sgrid, 256, 0, stream>>>(features, W1w, Vw, Vb, cb, wts);
    }

    softmax_kernel<<<Bdim, 256, 0, stream>>>(wts);

    dim3 cgrid(16, Bdim);
    context_kernel<<<cgrid, 256, 0, stream>>>(features, wts, ctx);
}

// Round 4
// 579.202 us; speedup vs baseline: 1.2000x; 1.2000x over previous
//
#include <hip/hip_runtime.h>
#include <cmath>

// Problem constants (from reference setup_inputs)
constexpr int Bdim = 64;
constexpr int Fdim = 4096;
constexpr int Edim = 256;
constexpr int Hdim = 512;
constexpr int Udim = 512;

typedef __attribute__((ext_vector_type(8))) short short8;   // 8 bf16 (16B)
typedef __attribute__((ext_vector_type(4))) float f32x4;

// ---------------------------------------------------------------------------
// Helpers
// ---------------------------------------------------------------------------
__device__ __forceinline__ unsigned short f2bf(float f) {
    unsigned int u = __float_as_uint(f);
    u += 0x7FFFu + ((u >> 16) & 1u);   // RNE; inputs finite
    return (unsigned short)(u >> 16);
}
__device__ __forceinline__ unsigned int pack2(float lo, float hi) {
    return (unsigned int)f2bf(lo) | ((unsigned int)f2bf(hi) << 16);
}
__device__ __forceinline__ float tanh_fast(float x) {
    float e = __expf(2.0f * x);
    return 1.0f - 2.0f * __builtin_amdgcn_rcpf(e + 1.0f);
}
// async global->LDS, 16B per lane; lds dest is wave-uniform base + lane*16
__device__ __forceinline__ void gload_lds16(const void* g, void* l) {
    __builtin_amdgcn_global_load_lds(
        (const __attribute__((address_space(1))) unsigned int*)g,
        (__attribute__((address_space(3))) unsigned int*)l, 16, 0, 0);
}

// ---------------------------------------------------------------------------
// Kernel 1: c[b][u] = W1_b[u] + W2_b[u] + sum_h hidden[b,h] * W2_w[h,u]
// ---------------------------------------------------------------------------
__global__ __launch_bounds__(256) void proj_h_kernel(
    const float* __restrict__ hidden, const float* __restrict__ W2,
    const float* __restrict__ W1b, const float* __restrict__ W2b,
    float* __restrict__ cb)
{
    const int b = blockIdx.x;
    const int u = blockIdx.y * 256 + threadIdx.x;
    const float* hb = hidden + (size_t)b * Hdim;
    float acc = 0.f;
    #pragma unroll 8
    for (int h = 0; h < Hdim; ++h)
        acc = fmaf(hb[h], W2[(size_t)h * Udim + u], acc);
    cb[(size_t)b * Udim + u] = acc + W1b[u] + W2b[u];
}

// ---------------------------------------------------------------------------
// Prep: W1 (E,U) fp32 -> transposed bf16 [U][E], with 16B-chunk XOR swizzle:
// k-chunk c (8 ushorts) of row u is stored at chunk index (c ^ (u & 7)).
// This makes the GEMM's ds_read_b128 frag reads 2-way (free) despite the
// unpadded 512B rows that global_load_lds requires.
// ---------------------------------------------------------------------------
__global__ __launch_bounds__(256) void w1t_kernel(
    const float* __restrict__ W1, unsigned short* __restrict__ Th)
{
    __shared__ unsigned short sT[64][72];
    const int e0 = blockIdx.x * 64, u0 = blockIdx.y * 64;
    const int tid = threadIdx.x;
    const int ue = tid & 63, er = tid >> 6;
    #pragma unroll
    for (int it = 0; it < 16; ++it) {
        const int e = er + it * 4;
        sT[ue][e] = f2bf(W1[(size_t)(e0 + e) * Udim + u0 + ue]);
    }
    __syncthreads();
    const int ur = tid >> 2, cq = tid & 3;
    const int u = u0 + ur, s = u & 7;
    const int cA = (e0 >> 3) + cq * 2;          // global 16B-chunk index
    uint4 a  = *(const uint4*)&sT[ur][cq * 16];
    uint4 b2 = *(const uint4*)&sT[ur][cq * 16 + 8];
    unsigned short* dst = Th + (size_t)u * Edim;
    *(uint4*)(dst + ((cA ^ s) << 3))       = a;
    *(uint4*)(dst + (((cA + 1) ^ s) << 3)) = b2;
}

// ---------------------------------------------------------------------------
// Kernel 2 (dominant): scores via bf16 MFMA.
// Block: 256 f-rows x full U; 4 waves, each 64 f-rows with A held in regs
// (af[4][8], staged via coalesced float4 loads + in-reg bf16 pack through a
// per-wave padded LDS scratch).  B staged per 128-u pass into shared LDS via
// global_load_lds (swizzled layout), 4 sub-passes of 32 u; fused tanh+V-dot.
// LDS 67.6 KB -> 2 blocks/CU.
// ---------------------------------------------------------------------------
__global__ __launch_bounds__(256, 2) void score_mfma3_kernel(
    const float* __restrict__ feat,            // [B][F][E] fp32
    const unsigned short* __restrict__ W1Ts,   // [U][E] bf16, chunk-swizzled
    const float* __restrict__ Vw, const float* __restrict__ Vb,
    const float* __restrict__ cb, float* __restrict__ scores)
{
    __shared__ unsigned short lds[33792];  // 67,584 B: A-stage (4x32x264) / B (128x256)

    const int b    = blockIdx.y;
    const int f0   = blockIdx.x * 256;
    const int tid  = threadIdx.x;
    const int lane = tid & 63;
    const int w    = tid >> 6;          // wave id, 64 f-rows each
    const int ln15 = lane & 15;
    const int kq   = lane >> 4;         // 0..3
    const int swz  = ln15 & 7;

    // ---- Phase A: stage+convert 64 f-rows into register fragments ----
    short8 af[4][8];
    {
        unsigned short* sAw = lds + w * 8448;   // 32 rows x 264 (per-wave)
        const float* gA = feat + ((size_t)(b * Fdim + f0 + w * 64)) * Edim;
        #pragma unroll
        for (int h = 0; h < 2; ++h) {
            #pragma unroll 8
            for (int r = 0; r < 32; ++r) {
                float4 v = *(const float4*)(gA + (size_t)(h * 32 + r) * Edim + lane * 4);
                uint2 p; p.x = pack2(v.x, v.y); p.y = pack2(v.z, v.w);
                *(uint2*)&sAw[r * 264 + lane * 4] = p;
            }
            #pragma unroll
            for (int m2 = 0; m2 < 2; ++m2)
                #pragma unroll
                for (int k8 = 0; k8 < 8; ++k8)
                    af[h * 2 + m2][k8] =
                        *(const short8*)&sAw[(m2 * 16 + ln15) * 264 + k8 * 32 + kq * 8];
        }
    }
    __syncthreads();   // all waves done with A scratch before B overwrites it

    float sacc[4][4] = {};   // [mi][r]
    const float* cbB = cb + (size_t)b * Udim;

    for (int up = 0; up < 4; ++up) {
        if (up) __syncthreads();   // previous sub-pass reads done
        // ---- stage B u-pass (128 rows x 512 B) via global_load_lds ----
        const char* gB = (const char*)(W1Ts + (size_t)up * 128 * Edim);
        #pragma unroll
        for (int t = 0; t < 16; ++t) {
            const int chunk = w * 16 + t;   // 64 x 1 KB
            gload_lds16(gB + (size_t)chunk * 1024 + lane * 16,
                        (char*)lds + chunk * 1024);
        }
        __syncthreads();

        #pragma unroll
        for (int sp = 0; sp < 4; ++sp) {
            const int ub = up * 128 + sp * 32;
            const float cu0 = cbB[ub + ln15],     cu1 = cbB[ub + 16 + ln15];
            const float vv0 = Vw[ub + ln15],      vv1 = Vw[ub + 16 + ln15];
            f32x4 acc[4][2] = {};
            #pragma unroll
            for (int k8 = 0; k8 < 8; ++k8) {
                const int co = ((k8 * 4 + kq) ^ swz) * 8;   // swizzled chunk
                short8 b0 = *(const short8*)&lds[(sp * 32 + ln15) * 256 + co];
                short8 b1 = *(const short8*)&lds[(sp * 32 + 16 + ln15) * 256 + co];
                #pragma unroll
                for (int mi = 0; mi < 4; ++mi) {
                    acc[mi][0] = __builtin_amdgcn_mfma_f32_16x16x32_bf16(
                        af[mi][k8], b0, acc[mi][0], 0, 0, 0);
                    acc[mi][1] = __builtin_amdgcn_mfma_f32_16x16x32_bf16(
                        af[mi][k8], b1, acc[mi][1], 0, 0, 0);
                }
            }
            // fused epilogue: tanh + V-dot into running per-f partials
            #pragma unroll
            for (int mi = 0; mi < 4; ++mi)
                #pragma unroll
                for (int r = 0; r < 4; ++r)
                    sacc[mi][r] += tanh_fast(acc[mi][0][r] + cu0) * vv0
                                 + tanh_fast(acc[mi][1][r] + cu1) * vv1;
        }
    }

    // ---- reduce over u-lanes (ln15), store scores (+Vb) ----
    const float vb = Vb[0];
    #pragma unroll
    for (int mi = 0; mi < 4; ++mi)
        #pragma unroll
        for (int r = 0; r < 4; ++r) {
            float s = sacc[mi][r];
            s += __shfl_xor(s, 1);
            s += __shfl_xor(s, 2);
            s += __shfl_xor(s, 4);
            s += __shfl_xor(s, 8);
            if (ln15 == 0)
                scores[(size_t)b * Fdim + f0 + w * 64 + mi * 16 + kq * 4 + r] = s + vb;
        }
}

// ---------------------------------------------------------------------------
// Fallback fp32 score kernel (round-1) — used only if ws too small
// ---------------------------------------------------------------------------
constexpr int TFt = 64;
constexpr int TUt = 64;
constexpr int LDR = Edim + 4;

__global__ __launch_bounds__(256) void score_kernel(
    const float* __restrict__ feat, const float* __restrict__ W1,
    const float* __restrict__ Vw, const float* __restrict__ Vb,
    const float* __restrict__ cb, float* __restrict__ scores)
{
    __shared__ float sA[TFt * LDR];
    __shared__ float sW[TUt * LDR];

    const int b   = blockIdx.y;
    const int f0  = blockIdx.x * TFt;
    const int tid = threadIdx.x;
    const int tf  = tid >> 4;
    const int tu  = tid & 15;

    {
        const float4* gA = (const float4*)(feat + ((size_t)b * Fdim + f0) * Edim);
        #pragma unroll
        for (int it = 0; it < 16; ++it) {
            const int i = tid + it * 256;
            const int f = i >> 6;
            const int qq = i & 63;
            const float4 v = gA[i];
            *(float4*)&sA[f * LDR + 4 * qq] = v;
        }
    }

    float sacc[4] = {0.f, 0.f, 0.f, 0.f};
    const float* cbb = cb + (size_t)b * Udim;

    for (int uc = 0; uc < Udim; uc += TUt) {
        __syncthreads();
        #pragma unroll
        for (int it = 0; it < 16; ++it) {
            const int i = tid + it * 256;
            const int e = i >> 4;
            const int qq = i & 15;
            const float4 v = *(const float4*)(W1 + (size_t)e * Udim + uc + 4 * qq);
            sW[(4 * qq + 0) * LDR + e] = v.x;
            sW[(4 * qq + 1) * LDR + e] = v.y;
            sW[(4 * qq + 2) * LDR + e] = v.z;
            sW[(4 * qq + 3) * LDR + e] = v.w;
        }
        __syncthreads();

        float acc[4][4] = {};
        #pragma unroll 4
        for (int e = 0; e < Edim; e += 4) {
            float4 a0 = *(const float4*)&sA[(tf +  0) * LDR + e];
            float4 a1 = *(const float4*)&sA[(tf + 16) * LDR + e];
            float4 a2 = *(const float4*)&sA[(tf + 32) * LDR + e];
            float4 a3 = *(const float4*)&sA[(tf + 48) * LDR + e];
            float4 w0 = *(const float4*)&sW[(tu +  0) * LDR + e];
            float4 w1 = *(const float4*)&sW[(tu + 16) * LDR + e];
            float4 w2 = *(const float4*)&sW[(tu + 32) * LDR + e];
            float4 w3 = *(const float4*)&sW[(tu + 48) * LDR + e];
            #define FMA4(i, j, A, W)                         \
                acc[i][j] = fmaf(A.x, W.x, acc[i][j]);       \
                acc[i][j] = fmaf(A.y, W.y, acc[i][j]);       \
                acc[i][j] = fmaf(A.z, W.z, acc[i][j]);       \
                acc[i][j] = fmaf(A.w, W.w, acc[i][j]);
            FMA4(0,0,a0,w0) FMA4(0,1,a0,w1) FMA4(0,2,a0,w2) FMA4(0,3,a0,w3)
            FMA4(1,0,a1,w0) FMA4(1,1,a1,w1) FMA4(1,2,a1,w2) FMA4(1,3,a1,w3)
            FMA4(2,0,a2,w0) FMA4(2,1,a2,w1) FMA4(2,2,a2,w2) FMA4(2,3,a2,w3)
            FMA4(3,0,a3,w0) FMA4(3,1,a3,w1) FMA4(3,2,a3,w2) FMA4(3,3,a3,w3)
            #undef FMA4
        }

        #pragma unroll
        for (int j = 0; j < 4; ++j) {
            const int u = uc + tu + 16 * j;
            const float vw = Vw[u];
            const float cuv = cbb[u];
            #pragma unroll
            for (int i = 0; i < 4; ++i)
                sacc[i] = fmaf(tanhf(acc[i][j] + cuv), vw, sacc[i]);
        }
    }

    const float vb = Vb[0];
    #pragma unroll
    for (int i = 0; i < 4; ++i) {
        float s = sacc[i];
        s += __shfl_xor(s, 1);
        s += __shfl_xor(s, 2);
        s += __shfl_xor(s, 4);
        s += __shfl_xor(s, 8);
        if (tu == 0)
            scores[(size_t)b * Fdim + f0 + tf + 16 * i] = s + vb;
    }
}

// ---------------------------------------------------------------------------
// Kernel 3: in-place softmax over F for each b
// ---------------------------------------------------------------------------
__global__ __launch_bounds__(256) void softmax_kernel(float* __restrict__ sc)
{
    __shared__ float red[256];
    const int b = blockIdx.x;
    const int tid = threadIdx.x;
    float* row = sc + (size_t)b * Fdim;

    float v[16];
    float m = -INFINITY;
    #pragma unroll
    for (int i = 0; i < 16; ++i) {
        v[i] = row[tid + 256 * i];
        m = fmaxf(m, v[i]);
    }
    red[tid] = m;
    __syncthreads();
    for (int s = 128; s > 0; s >>= 1) {
        if (tid < s) red[tid] = fmaxf(red[tid], red[tid + s]);
        __syncthreads();
    }
    m = red[0];
    __syncthreads();

    float sum = 0.f;
    #pragma unroll
    for (int i = 0; i < 16; ++i) {
        v[i] = expf(v[i] - m);
        sum += v[i];
    }
    red[tid] = sum;
    __syncthreads();
    for (int s = 128; s > 0; s >>= 1) {
        if (tid < s) red[tid] += red[tid + s];
        __syncthreads();
    }
    const float inv = 1.f / red[0];
    #pragma unroll
    for (int i = 0; i < 16; ++i)
        row[tid + 256 * i] = v[i] * inv;
}

// ---------------------------------------------------------------------------
// Kernel 4: context[b][e] = sum_f weights[b][f] * feat[b][f][e]
// ---------------------------------------------------------------------------
__global__ __launch_bounds__(256) void context_kernel(
    const float* __restrict__ feat, const float* __restrict__ wts,
    float* __restrict__ ctx)
{
    const int b  = blockIdx.y;
    const int fc = blockIdx.x;
    const int e  = threadIdx.x;

    const float* fp = feat + ((size_t)b * Fdim + (size_t)fc * 256) * Edim + e;
    const float* wp = wts + (size_t)b * Fdim + (size_t)fc * 256;

    float acc = 0.f;
    #pragma unroll 8
    for (int f = 0; f < 256; ++f)
        acc = fmaf(wp[f], fp[(size_t)f * Edim], acc);

    atomicAdd(&ctx[(size_t)b * Edim + e], acc);
}

// ---------------------------------------------------------------------------
extern "C" void kernel_launch(void* const* d_in, const int* in_sizes, int n_in,
                              void* d_out, int out_size, void* d_ws, size_t ws_size,
                              hipStream_t stream)
{
    const float* features = (const float*)d_in[0];
    const float* hidden   = (const float*)d_in[1];
    const float* W1w      = (const float*)d_in[2];
    const float* W1b      = (const float*)d_in[3];
    const float* W2w      = (const float*)d_in[4];
    const float* W2b      = (const float*)d_in[5];
    const float* Vw       = (const float*)d_in[6];
    const float* Vb       = (const float*)d_in[7];

    float* ctx = (float*)d_out;                       // (B,E)
    float* wts = (float*)d_out + (size_t)Bdim * Edim; // (B,F)

    // Workspace: cb (128 KiB) | W1Ts (256 KiB bf16 swizzled [U][E])
    float* cb = (float*)d_ws;
    unsigned short* W1Ts = (unsigned short*)((char*)d_ws + 131072);
    const size_t NEED = 131072 + (size_t)Udim * Edim * 2;

    hipMemsetAsync(ctx, 0, (size_t)Bdim * Edim * sizeof(float), stream);
    dim3 pgrid(Bdim, Udim / 256);
    proj_h_kernel<<<pgrid, 256, 0, stream>>>(hidden, W2w, W1b, W2b, cb);

    if (ws_size >= NEED) {
        dim3 tgrid(Edim / 64, Udim / 64);   // (4, 8)
        w1t_kernel<<<tgrid, 256, 0, stream>>>(W1w, W1Ts);
        dim3 sgrid(Fdim / 256, Bdim);       // (16, 64)
        score_mfma3_kernel<<<sgrid, 256, 0, stream>>>(features, W1Ts, Vw, Vb, cb, wts);
    } else {
        dim3 sgrid(Fdim / TFt, Bdim);
        score_kernel<<<sgrid, 256, 0, stream>>>(features, W1w, Vw, Vb, cb, wts);
    }

    softmax_kernel<<<Bdim, 256, 0, stream>>>(wts);

    dim3 cgrid(16, Bdim);
    context_kernel<<<cgrid, 256, 0, stream>>>(features, wts, ctx);
}

// Round 5
// 492.293 us; speedup vs baseline: 1.4118x; 1.1765x over previous
//
#include <hip/hip_runtime.h>
#include <cmath>

// Problem constants (from reference setup_inputs)
constexpr int Bdim = 64;
constexpr int Fdim = 4096;
constexpr int Edim = 256;
constexpr int Hdim = 512;
constexpr int Udim = 512;

typedef __attribute__((ext_vector_type(8))) short short8;   // 8 bf16 (16B)
typedef __attribute__((ext_vector_type(4))) float f32x4;

// ---------------------------------------------------------------------------
// Helpers
// ---------------------------------------------------------------------------
__device__ __forceinline__ unsigned short f2bf(float f) {
    unsigned int u = __float_as_uint(f);
    u += 0x7FFFu + ((u >> 16) & 1u);   // RNE; inputs finite
    return (unsigned short)(u >> 16);
}
__device__ __forceinline__ unsigned int pack2(float lo, float hi) {
    return (unsigned int)f2bf(lo) | ((unsigned int)f2bf(hi) << 16);
}
__device__ __forceinline__ float tanh_fast(float x) {
    float e = __expf(2.0f * x);
    return 1.0f - 2.0f * __builtin_amdgcn_rcpf(e + 1.0f);
}
// async global->LDS, 16B per lane; lds dest is wave-uniform base + lane*16
__device__ __forceinline__ void gload_lds16(const void* g, void* l) {
    __builtin_amdgcn_global_load_lds(
        (const __attribute__((address_space(1))) unsigned int*)g,
        (__attribute__((address_space(3))) unsigned int*)l, 16, 0, 0);
}

// ---------------------------------------------------------------------------
// Kernel 1: c[b][u] = W1_b[u] + W2_b[u] + sum_h hidden[b,h] * W2_w[h,u]
// ---------------------------------------------------------------------------
__global__ __launch_bounds__(256) void proj_h_kernel(
    const float* __restrict__ hidden, const float* __restrict__ W2,
    const float* __restrict__ W1b, const float* __restrict__ W2b,
    float* __restrict__ cb)
{
    const int b = blockIdx.x;
    const int u = blockIdx.y * 256 + threadIdx.x;
    const float* hb = hidden + (size_t)b * Hdim;
    float acc = 0.f;
    #pragma unroll 8
    for (int h = 0; h < Hdim; ++h)
        acc = fmaf(hb[h], W2[(size_t)h * Udim + u], acc);
    cb[(size_t)b * Udim + u] = acc + W1b[u] + W2b[u];
}

// ---------------------------------------------------------------------------
// Prep: W1 (E,U) fp32 -> transposed bf16 [U][E], with 16B-chunk XOR swizzle:
// k-chunk c of row u stored at chunk index (c ^ (u & 7)) so that the GEMM's
// ds_read_b128 frag reads stay ~conflict-free despite unpadded 512B rows
// (global_load_lds forbids padding).
// ---------------------------------------------------------------------------
__global__ __launch_bounds__(256) void w1t_kernel(
    const float* __restrict__ W1, unsigned short* __restrict__ Th)
{
    __shared__ unsigned short sT[64][72];
    const int e0 = blockIdx.x * 64, u0 = blockIdx.y * 64;
    const int tid = threadIdx.x;
    const int ue = tid & 63, er = tid >> 6;
    #pragma unroll
    for (int it = 0; it < 16; ++it) {
        const int e = er + it * 4;
        sT[ue][e] = f2bf(W1[(size_t)(e0 + e) * Udim + u0 + ue]);
    }
    __syncthreads();
    const int ur = tid >> 2, cq = tid & 3;
    const int u = u0 + ur, s = u & 7;
    const int cA = (e0 >> 3) + cq * 2;          // global 16B-chunk index
    uint4 a  = *(const uint4*)&sT[ur][cq * 16];
    uint4 b2 = *(const uint4*)&sT[ur][cq * 16 + 8];
    unsigned short* dst = Th + (size_t)u * Edim;
    *(uint4*)(dst + ((cA ^ s) << 3))       = a;
    *(uint4*)(dst + (((cA + 1) ^ s) << 3)) = b2;
}

// ---------------------------------------------------------------------------
// Kernel 2 (dominant): scores via bf16 MFMA, spill-free A-in-registers.
// Block: 128 f-rows x full U; 4 waves x 32 f-rows. A = af[2][8] (64 VGPRs),
// staged via 2 phases of 16 coalesced fp32 rows through per-wave LDS scratch
// + in-reg bf16 pack. B: 8 u-passes of 64 rows (32 KB) via global_load_lds
// into LDS shared by all waves (swizzled). Fused tanh+V-dot epilogue.
// LDS 33,792 B -> 3-4 blocks/CU.
// ---------------------------------------------------------------------------
__global__ __launch_bounds__(256, 2) void score_mfma4_kernel(
    const float* __restrict__ feat,            // [B][F][E] fp32
    const unsigned short* __restrict__ W1Ts,   // [U][E] bf16, chunk-swizzled
    const float* __restrict__ Vw, const float* __restrict__ Vb,
    const float* __restrict__ cb, float* __restrict__ scores)
{
    __shared__ unsigned short lds[16896];   // 33,792 B: A-scratch / B window

    const int b    = blockIdx.y;
    const int f0   = blockIdx.x * 128;
    const int tid  = threadIdx.x;
    const int lane = tid & 63;
    const int w    = tid >> 6;          // wave id; 32 f-rows each
    const int ln15 = lane & 15;
    const int kq   = lane >> 4;         // 0..3
    const int swz  = ln15 & 7;

    // ---- Phase A: stage+convert 32 f-rows into af[2][8] (64 VGPRs) ----
    short8 af[2][8];
    {
        unsigned short* sAw = lds + w * 4224;   // 16 rows x 264 per wave
        const float* gA = feat + ((size_t)(b * Fdim + f0 + w * 32)) * Edim;
        #pragma unroll
        for (int h = 0; h < 2; ++h) {
            #pragma unroll
            for (int r = 0; r < 16; ++r) {
                float4 v = *(const float4*)(gA + (size_t)(h * 16 + r) * Edim + lane * 4);
                uint2 p; p.x = pack2(v.x, v.y); p.y = pack2(v.z, v.w);
                *(uint2*)&sAw[r * 264 + lane * 4] = p;
            }
            #pragma unroll
            for (int k8 = 0; k8 < 8; ++k8)
                af[h][k8] = *(const short8*)&sAw[ln15 * 264 + k8 * 32 + kq * 8];
        }
    }
    __syncthreads();   // all waves done with A scratch before B overwrites it

    float sacc[2][4] = {};   // [mi][r]
    const float* cbB = cb + (size_t)b * Udim;

    for (int up = 0; up < 8; ++up) {
        if (up) __syncthreads();   // previous pass reads done
        // ---- stage B u-pass (64 rows x 512 B = 32 KB) via global_load_lds ----
        const char* gB = (const char*)(W1Ts + (size_t)up * 64 * Edim);
        #pragma unroll
        for (int t = 0; t < 8; ++t) {
            const int chunk = w * 8 + t;   // 32 x 1 KB
            gload_lds16(gB + (size_t)chunk * 1024 + lane * 16,
                        (char*)lds + chunk * 1024);
        }
        __syncthreads();

        #pragma unroll
        for (int sp = 0; sp < 2; ++sp) {
            const int ub = up * 64 + sp * 32;
            const float cu0 = cbB[ub + ln15],     cu1 = cbB[ub + 16 + ln15];
            const float vv0 = Vw[ub + ln15],      vv1 = Vw[ub + 16 + ln15];
            f32x4 acc[2][2] = {};
            #pragma unroll
            for (int k8 = 0; k8 < 8; ++k8) {
                const int co = ((k8 * 4 + kq) ^ swz) * 8;   // swizzled chunk
                short8 b0 = *(const short8*)&lds[(sp * 32 + ln15) * 256 + co];
                short8 b1 = *(const short8*)&lds[(sp * 32 + 16 + ln15) * 256 + co];
                #pragma unroll
                for (int mi = 0; mi < 2; ++mi) {
                    acc[mi][0] = __builtin_amdgcn_mfma_f32_16x16x32_bf16(
                        af[mi][k8], b0, acc[mi][0], 0, 0, 0);
                    acc[mi][1] = __builtin_amdgcn_mfma_f32_16x16x32_bf16(
                        af[mi][k8], b1, acc[mi][1], 0, 0, 0);
                }
            }
            // fused epilogue: tanh + V-dot into running per-f partials
            #pragma unroll
            for (int mi = 0; mi < 2; ++mi)
                #pragma unroll
                for (int r = 0; r < 4; ++r)
                    sacc[mi][r] += tanh_fast(acc[mi][0][r] + cu0) * vv0
                                 + tanh_fast(acc[mi][1][r] + cu1) * vv1;
        }
    }

    // ---- reduce over u-lanes (ln15), store scores (+Vb) ----
    const float vb = Vb[0];
    #pragma unroll
    for (int mi = 0; mi < 2; ++mi)
        #pragma unroll
        for (int r = 0; r < 4; ++r) {
            float s = sacc[mi][r];
            s += __shfl_xor(s, 1);
            s += __shfl_xor(s, 2);
            s += __shfl_xor(s, 4);
            s += __shfl_xor(s, 8);
            if (ln15 == 0)
                scores[(size_t)b * Fdim + f0 + w * 32 + mi * 16 + kq * 4 + r] = s + vb;
        }
}

// ---------------------------------------------------------------------------
// Fallback fp32 score kernel (round-1) — used only if ws too small
// ---------------------------------------------------------------------------
constexpr int TFt = 64;
constexpr int TUt = 64;
constexpr int LDR = Edim + 4;

__global__ __launch_bounds__(256) void score_kernel(
    const float* __restrict__ feat, const float* __restrict__ W1,
    const float* __restrict__ Vw, const float* __restrict__ Vb,
    const float* __restrict__ cb, float* __restrict__ scores)
{
    __shared__ float sA[TFt * LDR];
    __shared__ float sW[TUt * LDR];

    const int b   = blockIdx.y;
    const int f0  = blockIdx.x * TFt;
    const int tid = threadIdx.x;
    const int tf  = tid >> 4;
    const int tu  = tid & 15;

    {
        const float4* gA = (const float4*)(feat + ((size_t)b * Fdim + f0) * Edim);
        #pragma unroll
        for (int it = 0; it < 16; ++it) {
            const int i = tid + it * 256;
            const int f = i >> 6;
            const int qq = i & 63;
            const float4 v = gA[i];
            *(float4*)&sA[f * LDR + 4 * qq] = v;
        }
    }

    float sacc[4] = {0.f, 0.f, 0.f, 0.f};
    const float* cbb = cb + (size_t)b * Udim;

    for (int uc = 0; uc < Udim; uc += TUt) {
        __syncthreads();
        #pragma unroll
        for (int it = 0; it < 16; ++it) {
            const int i = tid + it * 256;
            const int e = i >> 4;
            const int qq = i & 15;
            const float4 v = *(const float4*)(W1 + (size_t)e * Udim + uc + 4 * qq);
            sW[(4 * qq + 0) * LDR + e] = v.x;
            sW[(4 * qq + 1) * LDR + e] = v.y;
            sW[(4 * qq + 2) * LDR + e] = v.z;
            sW[(4 * qq + 3) * LDR + e] = v.w;
        }
        __syncthreads();

        float acc[4][4] = {};
        #pragma unroll 4
        for (int e = 0; e < Edim; e += 4) {
            float4 a0 = *(const float4*)&sA[(tf +  0) * LDR + e];
            float4 a1 = *(const float4*)&sA[(tf + 16) * LDR + e];
            float4 a2 = *(const float4*)&sA[(tf + 32) * LDR + e];
            float4 a3 = *(const float4*)&sA[(tf + 48) * LDR + e];
            float4 w0 = *(const float4*)&sW[(tu +  0) * LDR + e];
            float4 w1 = *(const float4*)&sW[(tu + 16) * LDR + e];
            float4 w2 = *(const float4*)&sW[(tu + 32) * LDR + e];
            float4 w3 = *(const float4*)&sW[(tu + 48) * LDR + e];
            #define FMA4(i, j, A, W)                         \
                acc[i][j] = fmaf(A.x, W.x, acc[i][j]);       \
                acc[i][j] = fmaf(A.y, W.y, acc[i][j]);       \
                acc[i][j] = fmaf(A.z, W.z, acc[i][j]);       \
                acc[i][j] = fmaf(A.w, W.w, acc[i][j]);
            FMA4(0,0,a0,w0) FMA4(0,1,a0,w1) FMA4(0,2,a0,w2) FMA4(0,3,a0,w3)
            FMA4(1,0,a1,w0) FMA4(1,1,a1,w1) FMA4(1,2,a1,w2) FMA4(1,3,a1,w3)
            FMA4(2,0,a2,w0) FMA4(2,1,a2,w1) FMA4(2,2,a2,w2) FMA4(2,3,a2,w3)
            FMA4(3,0,a3,w0) FMA4(3,1,a3,w1) FMA4(3,2,a3,w2) FMA4(3,3,a3,w3)
            #undef FMA4
        }

        #pragma unroll
        for (int j = 0; j < 4; ++j) {
            const int u = uc + tu + 16 * j;
            const float vw = Vw[u];
            const float cuv = cbb[u];
            #pragma unroll
            for (int i = 0; i < 4; ++i)
                sacc[i] = fmaf(tanhf(acc[i][j] + cuv), vw, sacc[i]);
        }
    }

    const float vb = Vb[0];
    #pragma unroll
    for (int i = 0; i < 4; ++i) {
        float s = sacc[i];
        s += __shfl_xor(s, 1);
        s += __shfl_xor(s, 2);
        s += __shfl_xor(s, 4);
        s += __shfl_xor(s, 8);
        if (tu == 0)
            scores[(size_t)b * Fdim + f0 + tf + 16 * i] = s + vb;
    }
}

// ---------------------------------------------------------------------------
// Kernel 3: in-place softmax over F for each b
// ---------------------------------------------------------------------------
__global__ __launch_bounds__(256) void softmax_kernel(float* __restrict__ sc)
{
    __shared__ float red[256];
    const int b = blockIdx.x;
    const int tid = threadIdx.x;
    float* row = sc + (size_t)b * Fdim;

    float v[16];
    float m = -INFINITY;
    #pragma unroll
    for (int i = 0; i < 16; ++i) {
        v[i] = row[tid + 256 * i];
        m = fmaxf(m, v[i]);
    }
    red[tid] = m;
    __syncthreads();
    for (int s = 128; s > 0; s >>= 1) {
        if (tid < s) red[tid] = fmaxf(red[tid], red[tid + s]);
        __syncthreads();
    }
    m = red[0];
    __syncthreads();

    float sum = 0.f;
    #pragma unroll
    for (int i = 0; i < 16; ++i) {
        v[i] = expf(v[i] - m);
        sum += v[i];
    }
    red[tid] = sum;
    __syncthreads();
    for (int s = 128; s > 0; s >>= 1) {
        if (tid < s) red[tid] += red[tid + s];
        __syncthreads();
    }
    const float inv = 1.f / red[0];
    #pragma unroll
    for (int i = 0; i < 16; ++i)
        row[tid + 256 * i] = v[i] * inv;
}

// ---------------------------------------------------------------------------
// Kernel 4: context[b][e] = sum_f weights[b][f] * feat[b][f][e]
// ---------------------------------------------------------------------------
__global__ __launch_bounds__(256) void context_kernel(
    const float* __restrict__ feat, const float* __restrict__ wts,
    float* __restrict__ ctx)
{
    const int b  = blockIdx.y;
    const int fc = blockIdx.x;
    const int e  = threadIdx.x;

    const float* fp = feat + ((size_t)b * Fdim + (size_t)fc * 256) * Edim + e;
    const float* wp = wts + (size_t)b * Fdim + (size_t)fc * 256;

    float acc = 0.f;
    #pragma unroll 8
    for (int f = 0; f < 256; ++f)
        acc = fmaf(wp[f], fp[(size_t)f * Edim], acc);

    atomicAdd(&ctx[(size_t)b * Edim + e], acc);
}

// ---------------------------------------------------------------------------
extern "C" void kernel_launch(void* const* d_in, const int* in_sizes, int n_in,
                              void* d_out, int out_size, void* d_ws, size_t ws_size,
                              hipStream_t stream)
{
    const float* features = (const float*)d_in[0];
    const float* hidden   = (const float*)d_in[1];
    const float* W1w      = (const float*)d_in[2];
    const float* W1b      = (const float*)d_in[3];
    const float* W2w      = (const float*)d_in[4];
    const float* W2b      = (const float*)d_in[5];
    const float* Vw       = (const float*)d_in[6];
    const float* Vb       = (const float*)d_in[7];

    float* ctx = (float*)d_out;                       // (B,E)
    float* wts = (float*)d_out + (size_t)Bdim * Edim; // (B,F)

    // Workspace: cb (128 KiB) | W1Ts (256 KiB bf16 swizzled [U][E])
    float* cb = (float*)d_ws;
    unsigned short* W1Ts = (unsigned short*)((char*)d_ws + 131072);
    const size_t NEED = 131072 + (size_t)Udim * Edim * 2;

    hipMemsetAsync(ctx, 0, (size_t)Bdim * Edim * sizeof(float), stream);
    dim3 pgrid(Bdim, Udim / 256);
    proj_h_kernel<<<pgrid, 256, 0, stream>>>(hidden, W2w, W1b, W2b, cb);

    if (ws_size >= NEED) {
        dim3 tgrid(Edim / 64, Udim / 64);   // (4, 8)
        w1t_kernel<<<tgrid, 256, 0, stream>>>(W1w, W1Ts);
        dim3 sgrid(Fdim / 128, Bdim);       // (32, 64)
        score_mfma4_kernel<<<sgrid, 256, 0, stream>>>(features, W1Ts, Vw, Vb, cb, wts);
    } else {
        dim3 sgrid(Fdim / TFt, Bdim);
        score_kernel<<<sgrid, 256, 0, stream>>>(features, W1w, Vw, Vb, cb, wts);
    }

    softmax_kernel<<<Bdim, 256, 0, stream>>>(wts);

    dim3 cgrid(16, Bdim);
    context_kernel<<<cgrid, 256, 0, stream>>>(features, wts, ctx);
}